// Round 2
// baseline (1321.718 us; speedup 1.0000x reference)
//
#include <hip/hip_runtime.h>
#include <stdint.h>
#include <math.h>

#define DIM 4096
#define NH 32
#define NKV 8
#define HD 128
#define SEQ 2048
#define KVDIM (NKV * HD)   // 1024

typedef __bf16 bf16x8 __attribute__((ext_vector_type(8)));
typedef float floatx4 __attribute__((ext_vector_type(4)));
typedef uint16_t u16x8 __attribute__((ext_vector_type(8)));

__device__ __forceinline__ float b2f(uint16_t u) {
    union { uint32_t i; float f; } v; v.i = ((uint32_t)u) << 16; return v.f;
}
__device__ __forceinline__ uint16_t f2b(float f) {
    union { float f; uint32_t i; } v; v.f = f;
    uint32_t r = v.i + 0x7fffu + ((v.i >> 16) & 1u);   // RTNE
    return (uint16_t)(r >> 16);
}

// Load 8 logical bf16 elements starting at element index e of buffer p,
// where p is bf16 (isf32=false) or f32 (isf32=true; convert to bf16).
__device__ __forceinline__ u16x8 ldchunk(const void* p, bool isf32, size_t e) {
    if (isf32) {
        const float* fp = (const float*)p + e;
        u16x8 r;
#pragma unroll
        for (int j = 0; j < 8; ++j) r[j] = f2b(fp[j]);
        return r;
    }
    return *(const u16x8*)((const uint16_t*)p + e);
}

// ---------------------------------------------------------------------------
// dtype detector: interpret first 4096 elements of x as bf16. True bf16
// N(0,1) data -> 0 "bad"; f32 data misread as bf16 -> ~40% bad (random
// exponents in low halves). flag: 0 = bf16 inputs, 1 = f32 inputs.
// ---------------------------------------------------------------------------
__global__ void detect_k(const uint16_t* __restrict__ x, int* __restrict__ flag) {
    __shared__ int cnt;
    if (threadIdx.x == 0) cnt = 0;
    __syncthreads();
    int bad = 0;
    for (int i = threadIdx.x; i < 4096; i += 256) {
        float v = b2f(x[i]);
        if (!(fabsf(v) < 1e6f)) bad++;   // NaN compares false -> counted
    }
    atomicAdd(&cnt, bad);
    __syncthreads();
    if (threadIdx.x == 0) *flag = (cnt > 256) ? 1 : 0;
}

// ---------------------------------------------------------------------------
// NT GEMM: C[m][n] = sum_k A[m][k]*B[n][k]. A: M x K, B: N x K, C: M x ldc.
// fp32 accum, bf16 MFMA. BM=BN=128, BK=64, 256 thr (2x2 waves, 64x64/wave).
// Plain staging (no global_load_lds this round). LDS slot XOR-swizzled.
// a_dyn/b_dyn: that operand's dtype follows *flagp. out_dyn: C written as
// f32 when *flagp==1 (else bf16).
// ---------------------------------------------------------------------------
__global__ __launch_bounds__(256) void gemm_nt(const void* __restrict__ A,
                                               const void* __restrict__ B,
                                               void* __restrict__ C,
                                               int K, int ldc,
                                               const int* __restrict__ flagp,
                                               int a_dyn, int b_dyn, int out_dyn) {
    __shared__ uint16_t As[128 * 64];
    __shared__ uint16_t Bs[128 * 64];
    const int f = *flagp;
    const bool af32 = a_dyn && f, bf32 = b_dyn && f, of32 = out_dyn && f;
    const int tid = threadIdx.x;
    const int wave = tid >> 6, lane = tid & 63;
    const int wh = wave >> 1, ww = wave & 1;
    const int quad = lane >> 4, l16 = lane & 15;
    const int m0 = blockIdx.x * 128;
    const int n0 = blockIdx.y * 128;

    floatx4 acc[4][4] = {};

    for (int k0 = 0; k0 < K; k0 += 64) {
        __syncthreads();   // prior iteration's LDS reads done
#pragma unroll
        for (int it = 0; it < 4; ++it) {
            int id = tid + it * 256;          // 0..1023 chunk id
            int row = id >> 3, slot = id & 7;
            int c8 = ((slot ^ (row & 7)) << 3);
            u16x8 va = ldchunk(A, af32, (size_t)(m0 + row) * K + k0 + c8);
            *(u16x8*)(As + row * 64 + slot * 8) = va;
            u16x8 vb = ldchunk(B, bf32, (size_t)(n0 + row) * K + k0 + c8);
            *(u16x8*)(Bs + row * 64 + slot * 8) = vb;
        }
        __syncthreads();
#pragma unroll
        for (int ks = 0; ks < 2; ++ks) {
            bf16x8 af[4], bf[4];
#pragma unroll
            for (int mi = 0; mi < 4; ++mi) {
                int r = wh * 64 + mi * 16 + l16;
                int slot = (ks * 4 + quad) ^ (r & 7);
                af[mi] = *(const bf16x8*)(As + r * 64 + slot * 8);
            }
#pragma unroll
            for (int ni = 0; ni < 4; ++ni) {
                int r = ww * 64 + ni * 16 + l16;
                int slot = (ks * 4 + quad) ^ (r & 7);
                bf[ni] = *(const bf16x8*)(Bs + r * 64 + slot * 8);
            }
#pragma unroll
            for (int mi = 0; mi < 4; ++mi)
#pragma unroll
                for (int ni = 0; ni < 4; ++ni)
                    acc[mi][ni] = __builtin_amdgcn_mfma_f32_16x16x32_bf16(
                        af[mi], bf[ni], acc[mi][ni], 0, 0, 0);
        }
    }
    // epilogue: C/D layout row = quad*4 + i, col = lane&15
#pragma unroll
    for (int mi = 0; mi < 4; ++mi) {
#pragma unroll
        for (int ni = 0; ni < 4; ++ni) {
            int row = m0 + wh * 64 + mi * 16 + quad * 4;
            int col = n0 + ww * 64 + ni * 16 + l16;
            if (of32) {
#pragma unroll
                for (int i = 0; i < 4; ++i)
                    ((float*)C)[(size_t)(row + i) * ldc + col] = acc[mi][ni][i];
            } else {
#pragma unroll
                for (int i = 0; i < 4; ++i)
                    ((uint16_t*)C)[(size_t)(row + i) * ldc + col] = f2b(acc[mi][ni][i]);
            }
        }
    }
}

// ---------------------------------------------------------------------------
// RoPE in-place on [SEQ][heads*HD] bf16 buffer (interleaved even/odd pairs)
// ---------------------------------------------------------------------------
__global__ void rope_k(uint16_t* __restrict__ buf, int heads) {
    int id = blockIdx.x * blockDim.x + threadIdx.x;
    int i = id & 63;
    int h = (id >> 6) % heads;
    int t = id / (64 * heads);
    uint16_t* p = buf + (size_t)t * (heads * HD) + h * HD + 2 * i;
    float e = b2f(p[0]), o = b2f(p[1]);
    // freq = theta^(-2i/128); log2(500000) = 18.931568...
    float freq = exp2f(-(float)(2 * i) * (18.93156857f / 128.0f));
    float ang = (float)t * freq;
    float s, c;
    sincosf(ang, &s, &c);
    p[0] = f2b(e * c - o * s);
    p[1] = f2b(e * s + o * c);
}

// ---------------------------------------------------------------------------
// Flash attention (causal, GQA rep=4). One block = (head, 128-q-row tile).
// 256 threads, waves 2x2. LDS: Qs 32K, Ks 32K (K tile then P), Vt 32K
// (V transposed), reduce arrays. Plain staging everywhere. All bf16 buffers.
// ---------------------------------------------------------------------------
__global__ __launch_bounds__(256, 1) void attn_k(const uint16_t* __restrict__ Q,
                                                 const uint16_t* __restrict__ Kg,
                                                 const uint16_t* __restrict__ Vg,
                                                 uint16_t* __restrict__ O) {
    __shared__ uint16_t Qs[128 * 128];
    __shared__ uint16_t Ks[128 * 128];
    __shared__ uint16_t Vt[128 * 128];
    __shared__ float redm[2][128];
    __shared__ float reds[2][128];

    const int tid = threadIdx.x;
    const int wave = tid >> 6, lane = tid & 63;
    const int wh = wave >> 1, ww = wave & 1;
    const int quad = lane >> 4, l16 = lane & 15;

    const int qt = 15 - (blockIdx.x >> 5);   // heavy q-tiles first
    const int h = blockIdx.x & 31;
    const int kvh = h >> 2;
    const int q0 = qt * 128;

    // stage Q tile (plain): 16384 el, 256 thr x 8 chunks of 8
#pragma unroll
    for (int it = 0; it < 8; ++it) {
        int id = tid + it * 256;
        int row = id >> 4, slot = id & 15;
        int c8 = ((slot ^ (row & 7)) << 3);
        *(u16x8*)(Qs + row * 128 + slot * 8) =
            *(const u16x8*)(Q + (size_t)(q0 + row) * DIM + h * HD + c8);
    }

    floatx4 acc_o[4][4] = {};
    float m_run[4][4], l_run[4][4];
#pragma unroll
    for (int mi = 0; mi < 4; ++mi)
#pragma unroll
        for (int i = 0; i < 4; ++i) { m_run[mi][i] = -__builtin_inff(); l_run[mi][i] = 0.f; }

    const float scale = 0.08838834764831845f;  // 1/sqrt(128)
    const float LOG2E = 1.44269504f;

    for (int kt = 0; kt <= qt; ++kt) {
        const int k0 = kt * 128;
        __syncthreads();   // prior tile's P/Vt reads done before restage
        // stage K tile (plain)
#pragma unroll
        for (int it = 0; it < 8; ++it) {
            int id = tid + it * 256;
            int row = id >> 4, slot = id & 15;
            int c8 = ((slot ^ (row & 7)) << 3);
            *(u16x8*)(Ks + row * 128 + slot * 8) =
                *(const u16x8*)(Kg + (size_t)(k0 + row) * KVDIM + kvh * HD + c8);
        }
        // stage V transposed: Vt[d][key], key-chunk slot swizzled with (d&7)
        {
            int key = tid & 127;
            int dhalf = tid >> 7;
#pragma unroll
            for (int it = 0; it < 8; ++it) {
                int dc = it * 2 + dhalf;
                u16x8 v = *(const u16x8*)(Vg + (size_t)(k0 + key) * KVDIM + kvh * HD + dc * 8);
#pragma unroll
                for (int j = 0; j < 8; ++j) {
                    int d = dc * 8 + j;
                    Vt[d * 128 + (((key >> 3) ^ (d & 7)) << 3) + (key & 7)] = v[j];
                }
            }
        }
        __syncthreads();   // staging visible

        // S = Q K^T
        floatx4 acc_s[4][4] = {};
#pragma unroll
        for (int ks = 0; ks < 4; ++ks) {
            bf16x8 qf[4], kf[4];
#pragma unroll
            for (int mi = 0; mi < 4; ++mi) {
                int r = wh * 64 + mi * 16 + l16;
                int slot = (ks * 4 + quad) ^ (r & 7);
                qf[mi] = *(const bf16x8*)(Qs + r * 128 + slot * 8);
            }
#pragma unroll
            for (int ni = 0; ni < 4; ++ni) {
                int r = ww * 64 + ni * 16 + l16;
                int slot = (ks * 4 + quad) ^ (r & 7);
                kf[ni] = *(const bf16x8*)(Ks + r * 128 + slot * 8);
            }
#pragma unroll
            for (int mi = 0; mi < 4; ++mi)
#pragma unroll
                for (int ni = 0; ni < 4; ++ni)
                    acc_s[mi][ni] = __builtin_amdgcn_mfma_f32_16x16x32_bf16(
                        qf[mi], kf[ni], acc_s[mi][ni], 0, 0, 0);
        }

        // scale + causal mask
#pragma unroll
        for (int mi = 0; mi < 4; ++mi)
#pragma unroll
            for (int ni = 0; ni < 4; ++ni)
#pragma unroll
                for (int i = 0; i < 4; ++i) {
                    float s = acc_s[mi][ni][i] * scale;
                    if (kt == qt) {
                        int ql = wh * 64 + mi * 16 + quad * 4 + i;
                        int kl = ww * 64 + ni * 16 + l16;
                        if (kl > ql) s = -__builtin_inff();
                    }
                    acc_s[mi][ni][i] = s;
                }

        // wave-local row max (over this wave's 64 keys) -> cross-wave via LDS
#pragma unroll
        for (int mi = 0; mi < 4; ++mi)
#pragma unroll
            for (int i = 0; i < 4; ++i) {
                float v = fmaxf(fmaxf(acc_s[mi][0][i], acc_s[mi][1][i]),
                                fmaxf(acc_s[mi][2][i], acc_s[mi][3][i]));
#pragma unroll
                for (int off = 1; off < 16; off <<= 1)
                    v = fmaxf(v, __shfl_xor(v, off));
                if (l16 == 0) redm[ww][wh * 64 + mi * 16 + quad * 4 + i] = v;
            }
        __syncthreads();   // redm visible; all Ks reads done -> safe to write P

        float alpha[4][4], mnew[4][4];
#pragma unroll
        for (int mi = 0; mi < 4; ++mi)
#pragma unroll
            for (int i = 0; i < 4; ++i) {
                int row = wh * 64 + mi * 16 + quad * 4 + i;
                float tm = fmaxf(redm[0][row], redm[1][row]);
                float mn = fmaxf(m_run[mi][i], tm);
                alpha[mi][i] = exp2f((m_run[mi][i] - mn) * LOG2E);
                mnew[mi][i] = mn;
            }

        // p = exp(s - m) -> bf16 P into Ks; row sums
#pragma unroll
        for (int mi = 0; mi < 4; ++mi)
#pragma unroll
            for (int i = 0; i < 4; ++i) {
                int ql = wh * 64 + mi * 16 + quad * 4 + i;
                float sum = 0.f;
#pragma unroll
                for (int ni = 0; ni < 4; ++ni) {
                    float p = exp2f((acc_s[mi][ni][i] - mnew[mi][i]) * LOG2E);
                    sum += p;
                    int key = ww * 64 + ni * 16 + l16;
                    Ks[ql * 128 + (((key >> 3) ^ (ql & 7)) << 3) + (key & 7)] = f2b(p);
                }
#pragma unroll
                for (int off = 1; off < 16; off <<= 1)
                    sum += __shfl_xor(sum, off);
                if (l16 == 0) reds[ww][ql] = sum;
            }
        __syncthreads();   // P + sums visible

#pragma unroll
        for (int mi = 0; mi < 4; ++mi)
#pragma unroll
            for (int i = 0; i < 4; ++i) {
                int row = wh * 64 + mi * 16 + quad * 4 + i;
                l_run[mi][i] = l_run[mi][i] * alpha[mi][i] + reds[0][row] + reds[1][row];
                m_run[mi][i] = mnew[mi][i];
            }
#pragma unroll
        for (int mi = 0; mi < 4; ++mi)
#pragma unroll
            for (int ni = 0; ni < 4; ++ni)
#pragma unroll
                for (int i = 0; i < 4; ++i)
                    acc_o[mi][ni][i] *= alpha[mi][i];

        // O += P V ; P in Ks (A-operand), V^T in Vt (B-operand)
#pragma unroll
        for (int ks = 0; ks < 4; ++ks) {
            bf16x8 pf[4], vf[4];
#pragma unroll
            for (int mi = 0; mi < 4; ++mi) {
                int r = wh * 64 + mi * 16 + l16;
                int slot = (ks * 4 + quad) ^ (r & 7);
                pf[mi] = *(const bf16x8*)(Ks + r * 128 + slot * 8);
            }
#pragma unroll
            for (int ni = 0; ni < 4; ++ni) {
                int d = ww * 64 + ni * 16 + l16;
                int slot = (ks * 4 + quad) ^ (d & 7);
                vf[ni] = *(const bf16x8*)(Vt + d * 128 + slot * 8);
            }
#pragma unroll
            for (int mi = 0; mi < 4; ++mi)
#pragma unroll
                for (int ni = 0; ni < 4; ++ni)
                    acc_o[mi][ni] = __builtin_amdgcn_mfma_f32_16x16x32_bf16(
                        pf[mi], vf[ni], acc_o[mi][ni], 0, 0, 0);
        }
    }

    // epilogue
#pragma unroll
    for (int mi = 0; mi < 4; ++mi)
#pragma unroll
        for (int i = 0; i < 4; ++i) {
            float inv = 1.0f / l_run[mi][i];
            int row = q0 + wh * 64 + mi * 16 + quad * 4 + i;
#pragma unroll
            for (int ni = 0; ni < 4; ++ni) {
                int col = h * HD + ww * 64 + ni * 16 + l16;
                O[(size_t)row * DIM + col] = f2b(acc_o[mi][ni][i] * inv);
            }
        }
}

extern "C" void kernel_launch(void* const* d_in, const int* in_sizes, int n_in,
                              void* d_out, int out_size, void* d_ws, size_t ws_size,
                              hipStream_t stream) {
    const void* x  = d_in[0];
    const void* wq = d_in[1];
    const void* wk = d_in[2];
    const void* wv = d_in[3];
    const void* wo = d_in[4];

    // ws layout (minimal, ~25 MB): [flag 256B][Kb 4MB][Vb 4MB][Ab 16.8MB]
    int* flag = (int*)d_ws;
    uint16_t* Kb = (uint16_t*)((char*)d_ws + 256);
    uint16_t* Vb = Kb + (size_t)SEQ * KVDIM;
    uint16_t* Ab = Vb + (size_t)SEQ * KVDIM;
    // Q lives in d_out (dead before the final GEMM overwrites d_out)
    uint16_t* Qb = (uint16_t*)d_out;

    dim3 blk(256);
    detect_k<<<1, blk, 0, stream>>>((const uint16_t*)x, flag);
    gemm_nt<<<dim3(SEQ / 128, DIM / 128), blk, 0, stream>>>(x, wq, Qb, DIM, DIM, flag, 1, 1, 0);
    gemm_nt<<<dim3(SEQ / 128, KVDIM / 128), blk, 0, stream>>>(x, wk, Kb, DIM, KVDIM, flag, 1, 1, 0);
    gemm_nt<<<dim3(SEQ / 128, KVDIM / 128), blk, 0, stream>>>(x, wv, Vb, DIM, KVDIM, flag, 1, 1, 0);
    rope_k<<<(SEQ * NH * 64) / 256, 256, 0, stream>>>(Qb, NH);
    rope_k<<<(SEQ * NKV * 64) / 256, 256, 0, stream>>>(Kb, NKV);
    attn_k<<<NH * (SEQ / 128), 256, 0, stream>>>(Qb, Kb, Vb, Ab);
    gemm_nt<<<dim3(SEQ / 128, DIM / 128), blk, 0, stream>>>(Ab, wo, d_out, DIM, DIM, flag, 0, 1, 1);
}